// Round 5
// baseline (255.359 us; speedup 1.0000x reference)
//
#include <hip/hip_runtime.h>
#include <math.h>

#define H 64
#define W 64
#define C 128
#define NB 8
#define COUT 128
#define HWi 4096

typedef __attribute__((ext_vector_type(8))) short short8;
typedef __attribute__((ext_vector_type(8))) unsigned short ushort8;
typedef __attribute__((ext_vector_type(4))) unsigned short ushort4v;
typedef __attribute__((ext_vector_type(4))) float f32x4;
typedef __attribute__((ext_vector_type(2))) float f32x2;

__device__ __forceinline__ unsigned short f2bf(float f){
    unsigned u = __float_as_uint(f);
    unsigned r = (u + 0x7FFFu + ((u >> 16) & 1u)) >> 16;
    return (unsigned short)r;
}
__device__ __forceinline__ float bf2f(unsigned short u){
    return __uint_as_float(((unsigned)u) << 16);
}
__device__ __forceinline__ f32x2 up2(unsigned p){
    f32x2 r;
    r.x = __uint_as_float(p << 16);
    r.y = __uint_as_float(p & 0xFFFF0000u);
    return r;
}
__device__ __forceinline__ unsigned pk2(f32x2 v){
    return (unsigned)f2bf(v.x) | ((unsigned)f2bf(v.y) << 16);
}

// ---------- k_pre: fused x-transpose + weight prep + psum zero ----------
__global__ void k_pre(const float* __restrict__ x, unsigned short* __restrict__ xTp,
                      const float* __restrict__ w_reg, const float* __restrict__ w_off,
                      const float* __restrict__ w_mod, const float* __restrict__ b_off,
                      const float* __restrict__ b_mod,
                      unsigned short* __restrict__ wA, unsigned short* __restrict__ w27A,
                      float* __restrict__ biasom, float* __restrict__ psum){
    int tid = threadIdx.x;
    if (blockIdx.x >= 528){
        int i = (blockIdx.x - 528) * 256 + tid;
        if (i < 147456){
            int kc = i >> 12, rem = i & 4095, oc = rem >> 5, kkl = rem & 31;
            int kk = kc * 32 + kkl, k = kk >> 7, c = kk & 127;
            wA[i] = f2bf(w_reg[oc * 1152 + c * 9 + k]);
        } else if (i < 147456 + 36864){
            int j2 = i - 147456;
            int kc = j2 >> 10, rem = j2 & 1023, m = rem >> 5, kkl = rem & 31;
            int kk = kc * 32 + kkl, k = kk >> 7, c = kk & 127;
            float v = 0.f;
            if (m < 18) v = w_off[m * 1152 + c * 9 + k];
            else if (m < 27) v = w_mod[(m - 18) * 1152 + c * 9 + k];
            w27A[j2] = f2bf(v);
        } else if (i < 147456 + 36864 + 32){
            int m = i - 147456 - 36864;
            biasom[m] = (m < 18) ? b_off[m] : (m < 27 ? b_mod[m - 18] : 0.f);
        } else if (i < 147456 + 36864 + 32 + 256){
            psum[i - 147456 - 36864 - 32] = 0.f;
        }
        return;
    }
    int bidx = blockIdx.x;
    int b = bidx / 66, hp = bidx - b * 66;
    unsigned short* row = xTp + (size_t)(b * 66 + hp) * 66 * 128;
    if (hp == 0 || hp == 65){
        ushort8 z = {0,0,0,0,0,0,0,0};
        for (int i = tid; i < 66 * 128 / 8; i += 256) ((ushort8*)row)[i] = z;
        return;
    }
    int h = hp - 1;
    __shared__ unsigned s2[64 * 69];
    int w = tid & 63, cp = tid >> 6;
    for (int cc = 0; cc < 16; cc++){
        int c2 = cc * 4 + cp;
        int c = c2 * 2;
        float f0 = x[(size_t)(b * 128 + c)     * HWi + h * 64 + w];
        float f1 = x[(size_t)(b * 128 + c + 1) * HWi + h * 64 + w];
        s2[w * 69 + c2] = (unsigned)f2bf(f0) | ((unsigned)f2bf(f1) << 16);
    }
    __syncthreads();
    if (tid < 32){
        ushort8 z = {0,0,0,0,0,0,0,0};
        int wp = (tid < 16) ? 0 : 65;
        int sg = tid & 15;
        *(ushort8*)(row + wp * 128 + sg * 8) = z;
    }
    for (int it = tid; it < 1024; it += 256){
        int w2 = it >> 4, sg = it & 15;
        uint4 v;
        v.x = s2[w2 * 69 + sg * 4 + 0];
        v.y = s2[w2 * 69 + sg * 4 + 1];
        v.z = s2[w2 * 69 + sg * 4 + 2];
        v.w = s2[w2 * 69 + sg * 4 + 3];
        *(uint4*)(row + (w2 + 1) * 128 + sg * 8) = v;
    }
}

// ---------- k_gemm27: barrier-free, zero-LDS MFMA conv ----------
// block = 256 thr = 4 waves x 16px; grid 512 (row h of batch b); frags direct from global
__global__ __launch_bounds__(256) void k_gemm27(const unsigned short* __restrict__ xTp,
        const unsigned short* __restrict__ w27A, const float* __restrict__ biasom,
        unsigned short* __restrict__ OM){
    int tid = threadIdx.x;
    int n0 = blockIdx.x * 64;
    int b = n0 >> 12, h = (n0 >> 6) & 63;
    int wv = tid >> 6, lane = tid & 63, quad = lane >> 4, l16 = lane & 15;
    int px = wv * 16 + l16;
    f32x4 acc0 = {0.f,0.f,0.f,0.f}, acc1 = {0.f,0.f,0.f,0.f};
    #pragma unroll
    for (int k = 0; k < 9; k++){
        int ki = k / 3, kj = k - ki * 3;
        const unsigned short* brow = xTp + (size_t)((b * 66 + h + ki) * 66 + px + kj) * 128 + quad * 8;
        #pragma unroll
        for (int c4 = 0; c4 < 4; c4++){
            int kc = k * 4 + c4;
            const unsigned short* ab = w27A + kc * 1024 + quad * 8;
            short8 a0 = *(const short8*)(ab + l16 * 32);
            short8 a1 = *(const short8*)(ab + (16 + l16) * 32);
            short8 bf = *(const short8*)(brow + c4 * 32);
            acc0 = __builtin_amdgcn_mfma_f32_16x16x32_bf16(a0, bf, acc0, 0, 0, 0);
            acc1 = __builtin_amdgcn_mfma_f32_16x16x32_bf16(a1, bf, acc1, 0, 0, 0);
        }
    }
    int n = n0 + px;
    #pragma unroll
    for (int t = 0; t < 2; t++){
        f32x4 a = t ? acc1 : acc0;
        ushort4v o;
        #pragma unroll
        for (int r = 0; r < 4; r++){
            int oc = t * 16 + quad * 4 + r;
            float v = a[r] + biasom[oc];
            if (oc >= 18) v = 2.f / (1.f + expf(-v));
            o[r] = f2bf(v);
        }
        *(ushort4v*)(OM + n * 32 + t * 16 + quad * 4) = o;
    }
}

// ---------- k_gemm128: barrier-free deformable conv ----------
// 512 thr = 8 waves (ocq 4 x ng 2); tile 128oc x 64px; B-frags sampled per-lane in registers
__global__ __launch_bounds__(512) void k_gemm128(const unsigned short* __restrict__ xTp,
        const unsigned short* __restrict__ OM, const unsigned short* __restrict__ wA,
        const float* __restrict__ b_reg, unsigned short* __restrict__ ybf,
        float* __restrict__ psum){
    __shared__ char smem[35328];
    int*   s_a4 = (int*)smem;            // int4[576]   @0     (9216 B)
    float* s_w4 = (float*)(smem + 9216); // float4[576] @9216  (9216 B)

    int tid = threadIdx.x;
    int n0 = blockIdx.x * 64;
    int b = n0 >> 12, h = (n0 >> 6) & 63;

    for (int idx = tid; idx < 576; idx += 512){
        int k = idx >> 6, px = idx & 63;
        int n = n0 + px;
        float dy = bf2f(OM[n * 32 + 2 * k]);
        float dx = bf2f(OM[n * 32 + 2 * k + 1]);
        float m  = bf2f(OM[n * 32 + 18 + k]);
        int ki = k / 3, kj = k - ki * 3;
        float py  = (float)(h - 1 + ki) + dy;
        float pxf = (float)(px - 1 + kj) + dx;
        float y0f = floorf(py), x0f = floorf(pxf);
        float ly = py - y0f, lx = pxf - x0f;
        int iy0 = (int)y0f, ix0 = (int)x0f;
        int cy0 = min(max(iy0 + 1, 0), 65), cy1 = min(max(iy0 + 2, 0), 65);
        int cx0 = min(max(ix0 + 1, 0), 65), cx1 = min(max(ix0 + 2, 0), 65);
        int rb = b * 66 * 66;
        int4 ca;
        ca.x = ((rb + cy0 * 66) + cx0) * 128;
        ca.y = ((rb + cy0 * 66) + cx1) * 128;
        ca.z = ((rb + cy1 * 66) + cx0) * 128;
        ca.w = ((rb + cy1 * 66) + cx1) * 128;
        float4 cw;
        cw.x = (1.f - ly) * (1.f - lx) * m;
        cw.y = (1.f - ly) * lx * m;
        cw.z = ly * (1.f - lx) * m;
        cw.w = ly * lx * m;
        *(int4*)(s_a4 + idx * 4)   = ca;
        *(float4*)(s_w4 + idx * 4) = cw;
    }
    __syncthreads();

    int wv = tid >> 6, lane = tid & 63, quad = lane >> 4, l16 = lane & 15;
    int ocq = wv & 3, ng = wv >> 2;

    f32x4 acc00 = {0.f,0.f,0.f,0.f}, acc01 = {0.f,0.f,0.f,0.f};
    f32x4 acc10 = {0.f,0.f,0.f,0.f}, acc11 = {0.f,0.f,0.f,0.f};

    for (int k9 = 0; k9 < 9; k9++){
        __builtin_amdgcn_s_barrier();   // rendezvous only (no fence): keeps waves L1-coherent in time
        int i0 = k9 * 64 + ng * 32 + l16;
        int4   ca0 = *(const int4*)(s_a4 + i0 * 4);
        float4 cw0 = *(const float4*)(s_w4 + i0 * 4);
        int4   ca1 = *(const int4*)(s_a4 + (i0 + 16) * 4);
        float4 cw1 = *(const float4*)(s_w4 + (i0 + 16) * 4);
        #pragma unroll
        for (int c4 = 0; c4 < 4; c4++){
            int kc = k9 * 4 + c4;
            const unsigned short* ab = wA + kc * 4096 + quad * 8;
            short8 a0 = *(const short8*)(ab + (ocq * 32 + l16) * 32);
            short8 a1 = *(const short8*)(ab + (ocq * 32 + 16 + l16) * 32);
            int co = c4 * 32 + quad * 8;
            short8 b0, b1;
            {
                ushort8 r0 = *(const ushort8*)(xTp + ca0.x + co);
                ushort8 r1 = *(const ushort8*)(xTp + ca0.y + co);
                ushort8 r2 = *(const ushort8*)(xTp + ca0.z + co);
                ushort8 r3 = *(const ushort8*)(xTp + ca0.w + co);
                const unsigned* u0 = (const unsigned*)&r0;
                const unsigned* u1 = (const unsigned*)&r1;
                const unsigned* u2 = (const unsigned*)&r2;
                const unsigned* u3 = (const unsigned*)&r3;
                unsigned* op = (unsigned*)&b0;
                #pragma unroll
                for (int j = 0; j < 4; j++){
                    f32x2 v = cw0.x * up2(u0[j]);
                    v += cw0.y * up2(u1[j]);
                    v += cw0.z * up2(u2[j]);
                    v += cw0.w * up2(u3[j]);
                    op[j] = pk2(v);
                }
            }
            {
                ushort8 r0 = *(const ushort8*)(xTp + ca1.x + co);
                ushort8 r1 = *(const ushort8*)(xTp + ca1.y + co);
                ushort8 r2 = *(const ushort8*)(xTp + ca1.z + co);
                ushort8 r3 = *(const ushort8*)(xTp + ca1.w + co);
                const unsigned* u0 = (const unsigned*)&r0;
                const unsigned* u1 = (const unsigned*)&r1;
                const unsigned* u2 = (const unsigned*)&r2;
                const unsigned* u3 = (const unsigned*)&r3;
                unsigned* op = (unsigned*)&b1;
                #pragma unroll
                for (int j = 0; j < 4; j++){
                    f32x2 v = cw1.x * up2(u0[j]);
                    v += cw1.y * up2(u1[j]);
                    v += cw1.z * up2(u2[j]);
                    v += cw1.w * up2(u3[j]);
                    op[j] = pk2(v);
                }
            }
            acc00 = __builtin_amdgcn_mfma_f32_16x16x32_bf16(a0, b0, acc00, 0, 0, 0);
            acc01 = __builtin_amdgcn_mfma_f32_16x16x32_bf16(a0, b1, acc01, 0, 0, 0);
            acc10 = __builtin_amdgcn_mfma_f32_16x16x32_bf16(a1, b0, acc10, 0, 0, 0);
            acc11 = __builtin_amdgcn_mfma_f32_16x16x32_bf16(a1, b1, acc11, 0, 0, 0);
        }
    }

    __syncthreads();
    float* ls = (float*)smem;   // [128][69] fp32 = 35328 B (metadata no longer needed)
    int sp0 = h * 64;
    #pragma unroll
    for (int to = 0; to < 2; to++){
        #pragma unroll
        for (int tn = 0; tn < 2; tn++){
            f32x4 a = to ? (tn ? acc11 : acc10) : (tn ? acc01 : acc00);
            int nl = ng * 32 + tn * 16 + l16;
            #pragma unroll
            for (int r = 0; r < 4; r++){
                int oc = ocq * 32 + to * 16 + quad * 4 + r;
                float v = a[r] + b_reg[oc];
                ybf[(size_t)(b * 128 + oc) * HWi + sp0 + nl] = f2bf(v);
                ls[oc * 69 + nl] = v;
            }
        }
    }
    __syncthreads();
    if (tid < 128){
        int oc = tid;
        float s = 0.f, s2 = 0.f;
        #pragma unroll 8
        for (int nl = 0; nl < 64; nl++){
            float v = ls[oc * 69 + nl];
            s += v; s2 = fmaf(v, v, s2);
        }
        atomicAdd(&psum[oc], s);
        atomicAdd(&psum[128 + oc], s2);
    }
}

// ---------- k_apply: BN (stats inline from psum) + affine + relu -> fp32 ----------
__global__ void k_apply(const unsigned short* __restrict__ ybf, const float* __restrict__ psum,
                        const float* __restrict__ gamma, const float* __restrict__ beta,
                        float* __restrict__ out){
    int e8 = (blockIdx.x * 256 + threadIdx.x) * 8;
    int c = (e8 >> 12) & 127;
    ushort8 u = *(const ushort8*)(ybf + e8);
    float s = psum[c], s2 = psum[128 + c];
    float mean = s * (1.f / 32768.f);
    float var  = s2 * (1.f / 32768.f) - mean * mean;
    float rs = rsqrtf(var + 1e-5f);
    float g = gamma[c] * rs;
    float bt = beta[c] - mean * g;
    float4 lo, hi;
    lo.x = fmaxf(fmaf(bf2f(u[0]), g, bt), 0.f);
    lo.y = fmaxf(fmaf(bf2f(u[1]), g, bt), 0.f);
    lo.z = fmaxf(fmaf(bf2f(u[2]), g, bt), 0.f);
    lo.w = fmaxf(fmaf(bf2f(u[3]), g, bt), 0.f);
    hi.x = fmaxf(fmaf(bf2f(u[4]), g, bt), 0.f);
    hi.y = fmaxf(fmaf(bf2f(u[5]), g, bt), 0.f);
    hi.z = fmaxf(fmaf(bf2f(u[6]), g, bt), 0.f);
    hi.w = fmaxf(fmaf(bf2f(u[7]), g, bt), 0.f);
    *(float4*)(out + e8)     = lo;
    *(float4*)(out + e8 + 4) = hi;
}

extern "C" void kernel_launch(void* const* d_in, const int* in_sizes, int n_in,
                              void* d_out, int out_size, void* d_ws, size_t ws_size,
                              hipStream_t stream){
    const float* x     = (const float*)d_in[0];
    const float* w_off = (const float*)d_in[1];
    const float* b_off = (const float*)d_in[2];
    const float* w_mod = (const float*)d_in[3];
    const float* b_mod = (const float*)d_in[4];
    const float* w_reg = (const float*)d_in[5];
    const float* b_reg = (const float*)d_in[6];
    const float* gamma = (const float*)d_in[7];
    const float* beta  = (const float*)d_in[8];

    char* wsb = (char*)d_ws;
    unsigned short* xTp   = (unsigned short*)(wsb);                    // 8,921,088 B
    unsigned short* OM    = (unsigned short*)(wsb + 8921088);          // 2,097,152 B
    unsigned short* ybf   = (unsigned short*)(wsb + 11018240);         // 8,388,608 B
    unsigned short* wA    = (unsigned short*)(wsb + 19406848);         //   294,912 B
    unsigned short* w27A  = (unsigned short*)(wsb + 19701760);         //    73,728 B
    float*          biasom= (float*)(wsb + 19775488);                  //       128 B
    float*          psum  = (float*)(wsb + 19775616);                  //     1,024 B
    float* out = (float*)d_out;

    hipLaunchKernelGGL(k_pre,    dim3(1250), dim3(256), 0, stream, x, xTp, w_reg, w_off, w_mod, b_off, b_mod, wA, w27A, biasom, psum);
    hipLaunchKernelGGL(k_gemm27, dim3(512),  dim3(256), 0, stream, xTp, w27A, biasom, OM);
    hipLaunchKernelGGL(k_gemm128,dim3(512),  dim3(512), 0, stream, xTp, OM, wA, b_reg, ybf, psum);
    hipLaunchKernelGGL(k_apply,  dim3(2048), dim3(256), 0, stream, ybf, psum, gamma, beta, out);
}

// Round 6
// 208.219 us; speedup vs baseline: 1.2264x; 1.2264x over previous
//
#include <hip/hip_runtime.h>
#include <math.h>

#define H 64
#define W 64
#define C 128
#define NB 8
#define COUT 128
#define HWi 4096
#define PBu 68            // sB pitch in ushorts (136B): b64 writes conflict-free, b128 reads 2-way(free)

typedef __attribute__((ext_vector_type(8))) short short8;
typedef __attribute__((ext_vector_type(8))) unsigned short ushort8;
typedef __attribute__((ext_vector_type(4))) unsigned short ushort4v;
typedef __attribute__((ext_vector_type(4))) float f32x4;
typedef __attribute__((ext_vector_type(2))) float f32x2;

__device__ __forceinline__ unsigned short f2bf(float f){
    unsigned u = __float_as_uint(f);
    unsigned r = (u + 0x7FFFu + ((u >> 16) & 1u)) >> 16;
    return (unsigned short)r;
}
__device__ __forceinline__ float bf2f(unsigned short u){
    return __uint_as_float(((unsigned)u) << 16);
}
__device__ __forceinline__ f32x2 up2(unsigned p){
    f32x2 r;
    r.x = __uint_as_float(p << 16);
    r.y = __uint_as_float(p & 0xFFFF0000u);
    return r;
}
__device__ __forceinline__ unsigned pk2(f32x2 v){
    return (unsigned)f2bf(v.x) | ((unsigned)f2bf(v.y) << 16);
}

// ---------- k_pre: fused x-transpose (float4 reads) + weight prep + psum zero ----------
__global__ void k_pre(const float* __restrict__ x, unsigned short* __restrict__ xTp,
                      const float* __restrict__ w_reg, const float* __restrict__ w_off,
                      const float* __restrict__ w_mod, const float* __restrict__ b_off,
                      const float* __restrict__ b_mod,
                      unsigned short* __restrict__ wA, unsigned short* __restrict__ w27A,
                      float* __restrict__ biasom, float* __restrict__ psum){
    int tid = threadIdx.x;
    if (blockIdx.x >= 528){
        int i = (blockIdx.x - 528) * 256 + tid;
        if (i < 147456){
            int kc = i >> 12, rem = i & 4095, oc = rem >> 5, kkl = rem & 31;
            int kk = kc * 32 + kkl, k = kk >> 7, c = kk & 127;
            wA[i] = f2bf(w_reg[oc * 1152 + c * 9 + k]);
        } else if (i < 147456 + 36864){
            int j2 = i - 147456;
            int kc = j2 >> 10, rem = j2 & 1023, m = rem >> 5, kkl = rem & 31;
            int kk = kc * 32 + kkl, k = kk >> 7, c = kk & 127;
            float v = 0.f;
            if (m < 18) v = w_off[m * 1152 + c * 9 + k];
            else if (m < 27) v = w_mod[(m - 18) * 1152 + c * 9 + k];
            w27A[j2] = f2bf(v);
        } else if (i < 147456 + 36864 + 32){
            int m = i - 147456 - 36864;
            biasom[m] = (m < 18) ? b_off[m] : (m < 27 ? b_mod[m - 18] : 0.f);
        } else if (i < 147456 + 36864 + 32 + 256){
            psum[i - 147456 - 36864 - 32] = 0.f;
        }
        return;
    }
    int bidx = blockIdx.x;
    int b = bidx / 66, hp = bidx - b * 66;
    unsigned short* row = xTp + (size_t)(b * 66 + hp) * 66 * 128;
    if (hp == 0 || hp == 65){
        ushort8 z = {0,0,0,0,0,0,0,0};
        for (int i = tid; i < 66 * 128 / 8; i += 256) ((ushort8*)row)[i] = z;
        return;
    }
    int h = hp - 1;
    __shared__ unsigned s2[64 * 69];
    int w4 = tid & 15, co = tid >> 4;
    #pragma unroll
    for (int p4 = 0; p4 < 4; p4++){
        int c = p4 * 32 + co * 2;
        const float* base = x + (size_t)(b * 128 + c) * HWi + h * 64 + w4 * 4;
        float4 fa = *(const float4*)(base);
        float4 fb = *(const float4*)(base + HWi);
        int c2 = c >> 1;
        s2[(w4 * 4 + 0) * 69 + c2] = (unsigned)f2bf(fa.x) | ((unsigned)f2bf(fb.x) << 16);
        s2[(w4 * 4 + 1) * 69 + c2] = (unsigned)f2bf(fa.y) | ((unsigned)f2bf(fb.y) << 16);
        s2[(w4 * 4 + 2) * 69 + c2] = (unsigned)f2bf(fa.z) | ((unsigned)f2bf(fb.z) << 16);
        s2[(w4 * 4 + 3) * 69 + c2] = (unsigned)f2bf(fa.w) | ((unsigned)f2bf(fb.w) << 16);
    }
    __syncthreads();
    if (tid < 32){
        ushort8 z = {0,0,0,0,0,0,0,0};
        int wp = (tid < 16) ? 0 : 65;
        int sg = tid & 15;
        *(ushort8*)(row + wp * 128 + sg * 8) = z;
    }
    for (int it = tid; it < 1024; it += 256){
        int w2 = it >> 4, sg = it & 15;
        uint4 v;
        v.x = s2[w2 * 69 + sg * 4 + 0];
        v.y = s2[w2 * 69 + sg * 4 + 1];
        v.z = s2[w2 * 69 + sg * 4 + 2];
        v.w = s2[w2 * 69 + sg * 4 + 3];
        *(uint4*)(row + (w2 + 1) * 128 + sg * 8) = v;
    }
}

// ---------- k_main: fused offset-conv + metadata + deformable conv + BN partials ----------
// 512 thr = 8 waves; grid 512 (one per (b,h)); tile 128oc x 64px
__global__ __launch_bounds__(512) void k_main(const unsigned short* __restrict__ xTp,
        const unsigned short* __restrict__ wA, const unsigned short* __restrict__ w27A,
        const float* __restrict__ biasom, const float* __restrict__ b_reg,
        unsigned short* __restrict__ ybf, float* __restrict__ psum){
    __shared__ char smem[35840];
    float* s_om = (float*)smem;                    // [64][33] fp32 (phases 1-2; overlaps sB)
    unsigned short* sB = (unsigned short*)smem;    // [2][64][PBu] (phase 3; 8704 B each)
    int*   s_a4 = (int*)(smem + 17408);            // int4[576]
    float* s_w4 = (float*)(smem + 26624);          // float4[576]

    int tid = threadIdx.x;
    int n0 = blockIdx.x * 64;
    int b = n0 >> 12, h = (n0 >> 6) & 63;
    int wv = tid >> 6, lane = tid & 63, quad = lane >> 4, l16 = lane & 15;

    // ===== Phase 1: offset+modulator conv (M=32, N=64, K=1152), barrier-free =====
    {
        int slice = wv >> 1, mhalf = wv & 1;
        int pxp = slice * 16 + l16;
        f32x4 accO = {0.f, 0.f, 0.f, 0.f};
        #pragma unroll
        for (int k9 = 0; k9 < 9; k9++){
            int ki = k9 / 3, kj = k9 - ki * 3;
            const unsigned short* brow = xTp + (size_t)((b * 66 + h + ki) * 66 + pxp + kj) * 128 + quad * 8;
            #pragma unroll
            for (int c4 = 0; c4 < 4; c4++){
                int kc = k9 * 4 + c4;
                short8 aO = *(const short8*)(w27A + kc * 1024 + (mhalf * 16 + l16) * 32 + quad * 8);
                short8 bO = *(const short8*)(brow + c4 * 32);
                accO = __builtin_amdgcn_mfma_f32_16x16x32_bf16(aO, bO, accO, 0, 0, 0);
            }
        }
        #pragma unroll
        for (int r = 0; r < 4; r++){
            int ch = mhalf * 16 + quad * 4 + r;
            if (ch < 27){
                float v = accO[r] + biasom[ch];
                if (ch >= 18) v = 2.f / (1.f + expf(-v));
                s_om[pxp * 33 + ch] = v;
            }
        }
    }
    __syncthreads();

    // ===== Phase 2: sampling metadata (fp32 offsets from LDS) =====
    for (int idx = tid; idx < 576; idx += 512){
        int k = idx >> 6, px = idx & 63;
        float dy = s_om[px * 33 + 2 * k];
        float dx = s_om[px * 33 + 2 * k + 1];
        float m  = s_om[px * 33 + 18 + k];
        int ki = k / 3, kj = k - ki * 3;
        float py  = (float)(h - 1 + ki) + dy;
        float pxf = (float)(px - 1 + kj) + dx;
        float y0f = floorf(py), x0f = floorf(pxf);
        float ly = py - y0f, lx = pxf - x0f;
        int iy0 = (int)y0f, ix0 = (int)x0f;
        int cy0 = min(max(iy0 + 1, 0), 65), cy1 = min(max(iy0 + 2, 0), 65);
        int cx0 = min(max(ix0 + 1, 0), 65), cx1 = min(max(ix0 + 2, 0), 65);
        int rb = b * 66 * 66;
        int4 ca;
        ca.x = ((rb + cy0 * 66) + cx0) * 128;
        ca.y = ((rb + cy0 * 66) + cx1) * 128;
        ca.z = ((rb + cy1 * 66) + cx0) * 128;
        ca.w = ((rb + cy1 * 66) + cx1) * 128;
        float4 cw;
        cw.x = (1.f - ly) * (1.f - lx) * m;
        cw.y = (1.f - ly) * lx * m;
        cw.z = ly * (1.f - lx) * m;
        cw.w = ly * lx * m;
        *(int4*)(s_a4 + idx * 4)   = ca;
        *(float4*)(s_w4 + idx * 4) = cw;
    }
    __syncthreads();

    // ===== Phase 3: main GEMM, 36 iters, dbuf, loads issued AFTER the barrier =====
    int ocq = wv & 3, ng = wv >> 2;
    int px = tid & 63, cq = tid >> 6;

    f32x4 acc00 = {0.f,0.f,0.f,0.f}, acc01 = {0.f,0.f,0.f,0.f};
    f32x4 acc10 = {0.f,0.f,0.f,0.f}, acc11 = {0.f,0.f,0.f,0.f};

    ushort4v cr0, cr1, cr2, cr3;
    float w0, w1, w2, w3;
    auto loadCorners = [&](int kcn){
        int idx = (kcn >> 2) * 64 + px;
        int c = ((kcn & 3) << 5) + cq * 4;
        int4   ca = *(const int4*)(s_a4 + idx * 4);
        float4 cw = *(const float4*)(s_w4 + idx * 4);
        w0 = cw.x; w1 = cw.y; w2 = cw.z; w3 = cw.w;
        cr0 = *(const ushort4v*)(xTp + ca.x + c);
        cr1 = *(const ushort4v*)(xTp + ca.y + c);
        cr2 = *(const ushort4v*)(xTp + ca.z + c);
        cr3 = *(const ushort4v*)(xTp + ca.w + c);
    };
    loadCorners(0);

    for (int kc = 0; kc < 36; kc++){
        int p = kc & 1;
        unsigned short* sBp = sB + p * 4352;
        {   // bilinear 4 channels -> 8B LDS write (conflict-free at pitch 136B)
            const unsigned* u0 = (const unsigned*)&cr0;
            const unsigned* u1 = (const unsigned*)&cr1;
            const unsigned* u2 = (const unsigned*)&cr2;
            const unsigned* u3 = (const unsigned*)&cr3;
            uint2 wd;
            f32x2 v0 = w0 * up2(u0[0]);
            v0 += w1 * up2(u1[0]);
            v0 += w2 * up2(u2[0]);
            v0 += w3 * up2(u3[0]);
            f32x2 v1 = w0 * up2(u0[1]);
            v1 += w1 * up2(u1[1]);
            v1 += w2 * up2(u2[1]);
            v1 += w3 * up2(u3[1]);
            wd.x = pk2(v0); wd.y = pk2(v1);
            *(uint2*)(sBp + px * PBu + cq * 4) = wd;
        }
        __syncthreads();                    // nothing outstanding in vmem here
        if (kc + 1 < 36) loadCorners(kc + 1);   // consumed next iter (covered by MFMA phase)
        const unsigned short* ab = wA + kc * 4096;
        short8 a0 = *(const short8*)(ab + (ocq * 32 + l16) * 32 + quad * 8);
        short8 a1 = *(const short8*)(ab + (ocq * 32 + 16 + l16) * 32 + quad * 8);
        short8 b0 = *(const short8*)(sBp + (ng * 32 + l16) * PBu + quad * 8);
        short8 b1 = *(const short8*)(sBp + (ng * 32 + 16 + l16) * PBu + quad * 8);
        acc00 = __builtin_amdgcn_mfma_f32_16x16x32_bf16(a0, b0, acc00, 0, 0, 0);
        acc01 = __builtin_amdgcn_mfma_f32_16x16x32_bf16(a0, b1, acc01, 0, 0, 0);
        acc10 = __builtin_amdgcn_mfma_f32_16x16x32_bf16(a1, b0, acc10, 0, 0, 0);
        acc11 = __builtin_amdgcn_mfma_f32_16x16x32_bf16(a1, b1, acc11, 0, 0, 0);
    }

    __syncthreads();
    float* ls = (float*)smem;   // [128][69] fp32 = 35328 B (metadata no longer needed)
    int sp0 = h * 64;
    #pragma unroll
    for (int to = 0; to < 2; to++){
        #pragma unroll
        for (int tn = 0; tn < 2; tn++){
            f32x4 a = to ? (tn ? acc11 : acc10) : (tn ? acc01 : acc00);
            int nl = ng * 32 + tn * 16 + l16;
            #pragma unroll
            for (int r = 0; r < 4; r++){
                int oc = ocq * 32 + to * 16 + quad * 4 + r;
                float v = a[r] + b_reg[oc];
                ybf[(size_t)(b * 128 + oc) * HWi + sp0 + nl] = f2bf(v);
                ls[oc * 69 + nl] = v;
            }
        }
    }
    __syncthreads();
    if (tid < 128){
        int oc = tid;
        float s = 0.f, s2 = 0.f;
        #pragma unroll 8
        for (int nl = 0; nl < 64; nl++){
            float v = ls[oc * 69 + nl];
            s += v; s2 = fmaf(v, v, s2);
        }
        atomicAdd(&psum[oc], s);
        atomicAdd(&psum[128 + oc], s2);
    }
}

// ---------- k_apply: BN (stats inline from psum) + affine + relu -> fp32 ----------
__global__ void k_apply(const unsigned short* __restrict__ ybf, const float* __restrict__ psum,
                        const float* __restrict__ gamma, const float* __restrict__ beta,
                        float* __restrict__ out){
    int e8 = (blockIdx.x * 256 + threadIdx.x) * 8;
    int c = (e8 >> 12) & 127;
    ushort8 u = *(const ushort8*)(ybf + e8);
    float s = psum[c], s2 = psum[128 + c];
    float mean = s * (1.f / 32768.f);
    float var  = s2 * (1.f / 32768.f) - mean * mean;
    float rs = rsqrtf(var + 1e-5f);
    float g = gamma[c] * rs;
    float bt = beta[c] - mean * g;
    float4 lo, hi;
    lo.x = fmaxf(fmaf(bf2f(u[0]), g, bt), 0.f);
    lo.y = fmaxf(fmaf(bf2f(u[1]), g, bt), 0.f);
    lo.z = fmaxf(fmaf(bf2f(u[2]), g, bt), 0.f);
    lo.w = fmaxf(fmaf(bf2f(u[3]), g, bt), 0.f);
    hi.x = fmaxf(fmaf(bf2f(u[4]), g, bt), 0.f);
    hi.y = fmaxf(fmaf(bf2f(u[5]), g, bt), 0.f);
    hi.z = fmaxf(fmaf(bf2f(u[6]), g, bt), 0.f);
    hi.w = fmaxf(fmaf(bf2f(u[7]), g, bt), 0.f);
    *(float4*)(out + e8)     = lo;
    *(float4*)(out + e8 + 4) = hi;
}

extern "C" void kernel_launch(void* const* d_in, const int* in_sizes, int n_in,
                              void* d_out, int out_size, void* d_ws, size_t ws_size,
                              hipStream_t stream){
    const float* x     = (const float*)d_in[0];
    const float* w_off = (const float*)d_in[1];
    const float* b_off = (const float*)d_in[2];
    const float* w_mod = (const float*)d_in[3];
    const float* b_mod = (const float*)d_in[4];
    const float* w_reg = (const float*)d_in[5];
    const float* b_reg = (const float*)d_in[6];
    const float* gamma = (const float*)d_in[7];
    const float* beta  = (const float*)d_in[8];

    char* wsb = (char*)d_ws;
    unsigned short* xTp   = (unsigned short*)(wsb);                    // 8,921,088 B
    unsigned short* ybf   = (unsigned short*)(wsb + 8921088);          // 8,388,608 B
    unsigned short* wA    = (unsigned short*)(wsb + 17309696);         //   294,912 B
    unsigned short* w27A  = (unsigned short*)(wsb + 17604608);         //    73,728 B
    float*          biasom= (float*)(wsb + 17678336);                  //       128 B
    float*          psum  = (float*)(wsb + 17678464);                  //     1,024 B
    float* out = (float*)d_out;

    hipLaunchKernelGGL(k_pre,   dim3(1250), dim3(256), 0, stream, x, xTp, w_reg, w_off, w_mod, b_off, b_mod, wA, w27A, biasom, psum);
    hipLaunchKernelGGL(k_main,  dim3(512),  dim3(512), 0, stream, xTp, wA, w27A, biasom, b_reg, ybf, psum);
    hipLaunchKernelGGL(k_apply, dim3(2048), dim3(256), 0, stream, ybf, psum, gamma, beta, out);
}

// Round 7
// 162.608 us; speedup vs baseline: 1.5704x; 1.2805x over previous
//
#include <hip/hip_runtime.h>
#include <math.h>

#define H 64
#define W 64
#define C 128
#define NB 8
#define COUT 128
#define HWi 4096

typedef __attribute__((ext_vector_type(8))) short short8;
typedef __attribute__((ext_vector_type(8))) unsigned short ushort8;
typedef __attribute__((ext_vector_type(4))) unsigned short ushort4v;
typedef __attribute__((ext_vector_type(4))) float f32x4;
typedef __attribute__((ext_vector_type(2))) float f32x2;

__device__ __forceinline__ unsigned short f2bf(float f){
    unsigned u = __float_as_uint(f);
    unsigned r = (u + 0x7FFFu + ((u >> 16) & 1u)) >> 16;
    return (unsigned short)r;
}
__device__ __forceinline__ float bf2f(unsigned short u){
    return __uint_as_float(((unsigned)u) << 16);
}
__device__ __forceinline__ f32x2 up2(unsigned p){
    f32x2 r;
    r.x = __uint_as_float(p << 16);
    r.y = __uint_as_float(p & 0xFFFF0000u);
    return r;
}
// pack f32x2 -> bf16x2, round-half-up (3 VALU: add, add, v_perm)
__device__ __forceinline__ unsigned pk2r(f32x2 v){
    unsigned a = __float_as_uint(v.x) + 0x8000u;
    unsigned b = __float_as_uint(v.y) + 0x8000u;
    return __builtin_amdgcn_perm(b, a, 0x07060302);
}

// ---------- k_pre: x-transpose + weight swizzles + psum zero ----------
// wAv  [kc36][t8][lane64][j8]: A-frag for oc-tile t is one dense 16B/lane load
// w27Av[kc36][mh2][lane64][j8]
__global__ void k_pre(const float* __restrict__ x, unsigned short* __restrict__ xTp,
                      const float* __restrict__ w_reg, const float* __restrict__ w_off,
                      const float* __restrict__ w_mod, const float* __restrict__ b_off,
                      const float* __restrict__ b_mod,
                      unsigned short* __restrict__ wAv, unsigned short* __restrict__ w27Av,
                      float* __restrict__ biasom, float* __restrict__ psum){
    int tid = threadIdx.x;
    if (blockIdx.x >= 528){
        int i = (blockIdx.x - 528) * 256 + tid;
        if (i < 147456){
            int kc = i >> 12, rem = i & 4095;
            int t = rem >> 9, ln = (rem >> 3) & 63, j = i & 7;
            int oc = t * 16 + (ln & 15);
            int kkl = ((ln >> 4) << 3) + j;
            int kk = kc * 32 + kkl, k = kk >> 7, c = kk & 127;
            wAv[i] = f2bf(w_reg[oc * 1152 + c * 9 + k]);
        } else if (i < 147456 + 36864){
            int j2 = i - 147456;
            int kc = j2 >> 10, rem = j2 & 1023;
            int mh = rem >> 9, ln = (rem >> 3) & 63, j = j2 & 7;
            int m = mh * 16 + (ln & 15);
            int kkl = ((ln >> 4) << 3) + j;
            int kk = kc * 32 + kkl, k = kk >> 7, c = kk & 127;
            float v = 0.f;
            if (m < 18) v = w_off[m * 1152 + c * 9 + k];
            else if (m < 27) v = w_mod[(m - 18) * 1152 + c * 9 + k];
            w27Av[j2] = f2bf(v);
        } else if (i < 147456 + 36864 + 32){
            int m = i - 147456 - 36864;
            biasom[m] = (m < 18) ? b_off[m] : (m < 27 ? b_mod[m - 18] : 0.f);
        } else if (i < 147456 + 36864 + 32 + 256){
            psum[i - 147456 - 36864 - 32] = 0.f;
        }
        return;
    }
    int bidx = blockIdx.x;
    int b = bidx / 66, hp = bidx - b * 66;
    unsigned short* row = xTp + (size_t)(b * 66 + hp) * 66 * 128;
    if (hp == 0 || hp == 65){
        ushort8 z = {0,0,0,0,0,0,0,0};
        for (int i = tid; i < 66 * 128 / 8; i += 256) ((ushort8*)row)[i] = z;
        return;
    }
    int h = hp - 1;
    __shared__ unsigned s2[64 * 69];
    int w4 = tid & 15, co = tid >> 4;
    #pragma unroll
    for (int p4 = 0; p4 < 4; p4++){
        int c = p4 * 32 + co * 2;
        const float* base = x + (size_t)(b * 128 + c) * HWi + h * 64 + w4 * 4;
        float4 fa = *(const float4*)(base);
        float4 fb = *(const float4*)(base + HWi);
        int c2 = c >> 1;
        s2[(w4 * 4 + 0) * 69 + c2] = (unsigned)f2bf(fa.x) | ((unsigned)f2bf(fb.x) << 16);
        s2[(w4 * 4 + 1) * 69 + c2] = (unsigned)f2bf(fa.y) | ((unsigned)f2bf(fb.y) << 16);
        s2[(w4 * 4 + 2) * 69 + c2] = (unsigned)f2bf(fa.z) | ((unsigned)f2bf(fb.z) << 16);
        s2[(w4 * 4 + 3) * 69 + c2] = (unsigned)f2bf(fa.w) | ((unsigned)f2bf(fb.w) << 16);
    }
    __syncthreads();
    if (tid < 32){
        ushort8 z = {0,0,0,0,0,0,0,0};
        int wp = (tid < 16) ? 0 : 65;
        int sg = tid & 15;
        *(ushort8*)(row + wp * 128 + sg * 8) = z;
    }
    for (int it = tid; it < 1024; it += 256){
        int w2 = it >> 4, sg = it & 15;
        uint4 v;
        v.x = s2[w2 * 69 + sg * 4 + 0];
        v.y = s2[w2 * 69 + sg * 4 + 1];
        v.z = s2[w2 * 69 + sg * 4 + 2];
        v.w = s2[w2 * 69 + sg * 4 + 3];
        *(uint4*)(row + (w2 + 1) * 128 + sg * 8) = v;
    }
}

// ---------- k_main: fused offset-conv + metadata + barrier-free deform GEMM + BN partials ----
// 256 thr = 4 waves; each wave owns 16 px x ALL 128 oc (8 accs); B-frag sampled in-register.
__global__ __launch_bounds__(256) void k_main(const unsigned short* __restrict__ xTp,
        const unsigned short* __restrict__ wAv, const unsigned short* __restrict__ w27Av,
        const float* __restrict__ biasom, const float* __restrict__ b_reg,
        unsigned short* __restrict__ ybf, float* __restrict__ psum){
    __shared__ char smem[33536];
    float* s_om = (float*)smem;                 // [64][33] fp32 = 8448 B
    int*   s_a4 = (int*)(smem + 8448);          // int4[576]   = 9216 B
    float* s_w4 = (float*)(smem + 17664);       // float4[576] = 9216 B (end 26880)
    // epilogue reuses smem: float ls[128][65] = 33280 B

    int tid = threadIdx.x;
    int n0 = blockIdx.x * 64;
    int b = n0 >> 12, h = (n0 >> 6) & 63;
    int wv = tid >> 6, lane = tid & 63, quad = lane >> 4, l16 = lane & 15;
    int px0 = wv * 16;

    // ===== Phase 1: offset+modulator conv; wave wv: px slice, both m-halves; no barriers =====
    {
        f32x4 accA = {0.f,0.f,0.f,0.f}, accB = {0.f,0.f,0.f,0.f};
        #pragma unroll
        for (int k9 = 0; k9 < 9; k9++){
            int ki = k9 / 3, kj = k9 - ki * 3;
            const unsigned short* brow =
                xTp + (size_t)((b * 66 + h + ki) * 66 + px0 + l16 + kj) * 128 + quad * 8;
            #pragma unroll
            for (int c4 = 0; c4 < 4; c4++){
                int kc = k9 * 4 + c4;
                short8 bO = *(const short8*)(brow + c4 * 32);
                short8 a0 = *(const short8*)(w27Av + kc * 1024 + lane * 8);
                short8 a1 = *(const short8*)(w27Av + kc * 1024 + 512 + lane * 8);
                accA = __builtin_amdgcn_mfma_f32_16x16x32_bf16(a0, bO, accA, 0, 0, 0);
                accB = __builtin_amdgcn_mfma_f32_16x16x32_bf16(a1, bO, accB, 0, 0, 0);
            }
        }
        int pxl = px0 + l16;
        #pragma unroll
        for (int r = 0; r < 4; r++){
            int ch = quad * 4 + r;                       // 0..15: always offset channels
            s_om[pxl * 33 + ch] = accA[r] + biasom[ch];
        }
        #pragma unroll
        for (int r = 0; r < 4; r++){
            int ch = 16 + quad * 4 + r;                  // 16..31: keep <27, sigmoid >=18
            if (ch < 27){
                float v = accB[r] + biasom[ch];
                if (ch >= 18) v = 2.f / (1.f + expf(-v));
                s_om[pxl * 33 + ch] = v;
            }
        }
    }
    __syncthreads();

    // ===== Phase 2: sampling metadata =====
    for (int idx = tid; idx < 576; idx += 256){
        int k = idx >> 6, px = idx & 63;
        float dy = s_om[px * 33 + 2 * k];
        float dx = s_om[px * 33 + 2 * k + 1];
        float m  = s_om[px * 33 + 18 + k];
        int ki = k / 3, kj = k - ki * 3;
        float py  = (float)(h - 1 + ki) + dy;
        float pxf = (float)(px - 1 + kj) + dx;
        float y0f = floorf(py), x0f = floorf(pxf);
        float ly = py - y0f, lx = pxf - x0f;
        int iy0 = (int)y0f, ix0 = (int)x0f;
        int cy0 = min(max(iy0 + 1, 0), 65), cy1 = min(max(iy0 + 2, 0), 65);
        int cx0 = min(max(ix0 + 1, 0), 65), cx1 = min(max(ix0 + 2, 0), 65);
        int rb = b * 66 * 66;
        int4 ca;
        ca.x = ((rb + cy0 * 66) + cx0) * 128;
        ca.y = ((rb + cy0 * 66) + cx1) * 128;
        ca.z = ((rb + cy1 * 66) + cx0) * 128;
        ca.w = ((rb + cy1 * 66) + cx1) * 128;
        float4 cw;
        cw.x = (1.f - ly) * (1.f - lx) * m;
        cw.y = (1.f - ly) * lx * m;
        cw.z = ly * (1.f - lx) * m;
        cw.w = ly * lx * m;
        *(int4*)(s_a4 + idx * 4)   = ca;
        *(float4*)(s_w4 + idx * 4) = cw;
    }
    __syncthreads();

    // ===== Phase 3: barrier-free GEMM; wave = 16px x 128oc; 1-chunk-ahead prefetch =====
    int px = px0 + l16;     // this lane's pixel
    int cq = quad;          // this lane's 8-channel group within the 32-ch chunk

    f32x4 acc[8];
    #pragma unroll
    for (int t = 0; t < 8; t++) acc[t] = (f32x4){0.f,0.f,0.f,0.f};

    int4 ca; float4 cw, wS;
    short8 aC[8], aN[8];
    ushort8 cC[4], cN[4];

    {   // init chunk 0
        int i0 = px * 4;
        ca = *(const int4*)(s_a4 + i0);
        cw = *(const float4*)(s_w4 + i0);
        wS = cw;
        const unsigned short* ab = wAv + lane * 8;
        #pragma unroll
        for (int t = 0; t < 8; t++) aC[t] = *(const short8*)(ab + t * 512);
        int co = cq * 8;
        cC[0] = *(const ushort8*)(xTp + ca.x + co);
        cC[1] = *(const ushort8*)(xTp + ca.y + co);
        cC[2] = *(const ushort8*)(xTp + ca.z + co);
        cC[3] = *(const ushort8*)(xTp + ca.w + co);
    }

    #pragma unroll 4
    for (int kc = 0; kc < 36; kc++){
        // build B-frag in-register from current corners
        short8 bfr;
        {
            unsigned* op = (unsigned*)&bfr;
            const unsigned* u0 = (const unsigned*)&cC[0];
            const unsigned* u1 = (const unsigned*)&cC[1];
            const unsigned* u2 = (const unsigned*)&cC[2];
            const unsigned* u3 = (const unsigned*)&cC[3];
            #pragma unroll
            for (int j = 0; j < 4; j++){
                f32x2 v = wS.x * up2(u0[j]);
                v += wS.y * up2(u1[j]);
                v += wS.z * up2(u2[j]);
                v += wS.w * up2(u3[j]);
                op[j] = pk2r(v);
            }
        }
        // prefetch chunk kc+1 (metadata at k9 boundary, corners, A-frags)
        if (kc + 1 < 36){
            if (((kc + 1) & 3) == 0){
                int i0 = (((kc + 1) >> 2) * 64 + px) * 4;
                ca = *(const int4*)(s_a4 + i0);
                cw = *(const float4*)(s_w4 + i0);
            }
            int co = ((kc + 1) & 3) * 32 + cq * 8;
            cN[0] = *(const ushort8*)(xTp + ca.x + co);
            cN[1] = *(const ushort8*)(xTp + ca.y + co);
            cN[2] = *(const ushort8*)(xTp + ca.z + co);
            cN[3] = *(const ushort8*)(xTp + ca.w + co);
            const unsigned short* ab = wAv + (kc + 1) * 4096 + lane * 8;
            #pragma unroll
            for (int t = 0; t < 8; t++) aN[t] = *(const short8*)(ab + t * 512);
        }
        // 8 MFMAs (independent accumulators)
        #pragma unroll
        for (int t = 0; t < 8; t++)
            acc[t] = __builtin_amdgcn_mfma_f32_16x16x32_bf16(aC[t], bfr, acc[t], 0, 0, 0);
        // shift pipeline
        #pragma unroll
        for (int t = 0; t < 8; t++) aC[t] = aN[t];
        cC[0] = cN[0]; cC[1] = cN[1]; cC[2] = cN[2]; cC[3] = cN[3];
        wS = cw;
    }

    __syncthreads();
    float* ls = (float*)smem;   // [128][65] fp32 = 33280 B
    int sp0 = h * 64;
    #pragma unroll
    for (int t = 0; t < 8; t++){
        #pragma unroll
        for (int r = 0; r < 4; r++){
            int oc = t * 16 + quad * 4 + r;
            float v = acc[t][r] + b_reg[oc];
            ybf[(size_t)(b * 128 + oc) * HWi + sp0 + px] = f2bf(v);
            ls[oc * 65 + px] = v;
        }
    }
    __syncthreads();
    if (tid < 128){
        int oc = tid;
        float s = 0.f, s2 = 0.f;
        #pragma unroll 8
        for (int nl = 0; nl < 64; nl++){
            float v = ls[oc * 65 + nl];
            s += v; s2 = fmaf(v, v, s2);
        }
        atomicAdd(&psum[oc], s);
        atomicAdd(&psum[128 + oc], s2);
    }
}

// ---------- k_apply: BN (stats inline from psum) + affine + relu -> fp32 ----------
__global__ void k_apply(const unsigned short* __restrict__ ybf, const float* __restrict__ psum,
                        const float* __restrict__ gamma, const float* __restrict__ beta,
                        float* __restrict__ out){
    int e8 = (blockIdx.x * 256 + threadIdx.x) * 8;
    int c = (e8 >> 12) & 127;
    ushort8 u = *(const ushort8*)(ybf + e8);
    float s = psum[c], s2 = psum[128 + c];
    float mean = s * (1.f / 32768.f);
    float var  = s2 * (1.f / 32768.f) - mean * mean;
    float rs = rsqrtf(var + 1e-5f);
    float g = gamma[c] * rs;
    float bt = beta[c] - mean * g;
    float4 lo, hi;
    lo.x = fmaxf(fmaf(bf2f(u[0]), g, bt), 0.f);
    lo.y = fmaxf(fmaf(bf2f(u[1]), g, bt), 0.f);
    lo.z = fmaxf(fmaf(bf2f(u[2]), g, bt), 0.f);
    lo.w = fmaxf(fmaf(bf2f(u[3]), g, bt), 0.f);
    hi.x = fmaxf(fmaf(bf2f(u[4]), g, bt), 0.f);
    hi.y = fmaxf(fmaf(bf2f(u[5]), g, bt), 0.f);
    hi.z = fmaxf(fmaf(bf2f(u[6]), g, bt), 0.f);
    hi.w = fmaxf(fmaf(bf2f(u[7]), g, bt), 0.f);
    *(float4*)(out + e8)     = lo;
    *(float4*)(out + e8 + 4) = hi;
}

extern "C" void kernel_launch(void* const* d_in, const int* in_sizes, int n_in,
                              void* d_out, int out_size, void* d_ws, size_t ws_size,
                              hipStream_t stream){
    const float* x     = (const float*)d_in[0];
    const float* w_off = (const float*)d_in[1];
    const float* b_off = (const float*)d_in[2];
    const float* w_mod = (const float*)d_in[3];
    const float* b_mod = (const float*)d_in[4];
    const float* w_reg = (const float*)d_in[5];
    const float* b_reg = (const float*)d_in[6];
    const float* gamma = (const float*)d_in[7];
    const float* beta  = (const float*)d_in[8];

    char* wsb = (char*)d_ws;
    unsigned short* xTp   = (unsigned short*)(wsb);                    // 8,921,088 B
    unsigned short* ybf   = (unsigned short*)(wsb + 8921088);          // 8,388,608 B
    unsigned short* wAv   = (unsigned short*)(wsb + 17309696);         //   294,912 B
    unsigned short* w27Av = (unsigned short*)(wsb + 17604608);         //    73,728 B
    float*          biasom= (float*)(wsb + 17678336);                  //       128 B
    float*          psum  = (float*)(wsb + 17678464);                  //     1,024 B
    float* out = (float*)d_out;

    hipLaunchKernelGGL(k_pre,   dim3(1250), dim3(256), 0, stream, x, xTp, w_reg, w_off, w_mod, b_off, b_mod, wAv, w27Av, biasom, psum);
    hipLaunchKernelGGL(k_main,  dim3(512),  dim3(256), 0, stream, xTp, wAv, w27Av, biasom, b_reg, ybf, psum);
    hipLaunchKernelGGL(k_apply, dim3(2048), dim3(256), 0, stream, ybf, psum, gamma, beta, out);
}